// Round 1
// baseline (1254.611 us; speedup 1.0000x reference)
//
#include <hip/hip_runtime.h>

#define BIGF 1e20f
#define VF   1e10f

constexpr float SQ2 = 1.41421356237309515f;  // rounds to fp32 0x3FB504F3, same as jnp.sqrt(2.0)

// ---------------------------------------------------------------------------
// K1: binarize + channel max + dist init.  maps 0..15 = pred, 16..31 = target
// ---------------------------------------------------------------------------
__global__ __launch_bounds__(256) void k_init(const float* __restrict__ pred,
                                              const float* __restrict__ tgt,
                                              float* __restrict__ bufA,
                                              float* __restrict__ acc)
{
    if (blockIdx.x == 0 && threadIdx.x == 0) *acc = 0.0f;
    int idx = blockIdx.x * 256 + threadIdx.x;          // 0 .. 16*262144-1
    int b   = idx >> 18;                               // item
    int pix = idx & 262143;
    long base = (long)b * 3 * 262144 + pix;

    float p0 = pred[base], p1 = pred[base + 262144], p2 = pred[base + 2 * 262144];
    // pred01 = (p+1)/2 ; bin = pred01 >= 0.7  (exact reference predicate)
    bool fgP = ((p0 + 1.0f) * 0.5f >= 0.7f) ||
               ((p1 + 1.0f) * 0.5f >= 0.7f) ||
               ((p2 + 1.0f) * 0.5f >= 0.7f);

    float t0 = tgt[base], t1 = tgt[base + 262144], t2 = tgt[base + 2 * 262144];
    float mt = fmaxf(fmaxf(t0, t1), t2);               // exactly 0.0 or 1.0

    bufA[(long)b * 262144 + pix]        = fgP ? 0.0f : VF;   // V*(1-comb_pred)
    bufA[(long)(16 + b) * 262144 + pix] = VF * (1.0f - mt);  // V*(1-comb_tgt)
}

// ---------------------------------------------------------------------------
// K2: chamfer sweeps.  One block (512 threads) per map; thread t owns col t.
// ---------------------------------------------------------------------------
__device__ __forceinline__ void sweep_down(float* __restrict__ map, float (*sbuf)[514])
{
    int t = threadIdx.x;
    if (t < 2) { sbuf[0][t * 513] = BIGF; sbuf[1][t * 513] = BIGF; }
    sbuf[0][t + 1] = map[t];
    __syncthreads();
    float cur = map[512 + t];
    for (int r = 1; r < 512; ++r) {
        float nxt = (r < 511) ? map[(r + 1) * 512 + t] : 0.0f;  // prefetch
        const float* pv = sbuf[(r - 1) & 1];
        float nv = fminf(fminf(cur, pv[t + 1] + 1.0f),
                         fminf(pv[t], pv[t + 2]) + SQ2);
        sbuf[r & 1][t + 1] = nv;
        map[r * 512 + t] = nv;
        __syncthreads();
        cur = nxt;
    }
}

__device__ __forceinline__ void sweep_up(float* __restrict__ map, float (*sbuf)[514])
{
    int t = threadIdx.x;
    if (t < 2) { sbuf[0][t * 513] = BIGF; sbuf[1][t * 513] = BIGF; }
    sbuf[1][t + 1] = map[511 * 512 + t];     // row 511 parity = 1
    __syncthreads();
    float cur = map[510 * 512 + t];
    for (int r = 510; r >= 0; --r) {
        float nxt = (r > 0) ? map[(r - 1) * 512 + t] : 0.0f;
        const float* pv = sbuf[(r + 1) & 1];
        float nv = fminf(fminf(cur, pv[t + 1] + 1.0f),
                         fminf(pv[t], pv[t + 2]) + SQ2);
        sbuf[r & 1][t + 1] = nv;
        map[r * 512 + t] = nv;
        __syncthreads();
        cur = nxt;
    }
}

__device__ __forceinline__ void transpose512(const float* __restrict__ src,
                                             float* __restrict__ dst,
                                             float (*tile)[65])
{
    int t = threadIdx.x;
    int x = t & 63, y0 = t >> 6;            // y0 in 0..7
    for (int tb = 0; tb < 64; ++tb) {
        int ti = tb >> 3, tj = tb & 7;
        __syncthreads();
        #pragma unroll
        for (int k = 0; k < 8; ++k) {
            int y = y0 + k * 8;
            tile[y][x] = src[(ti * 64 + y) * 512 + tj * 64 + x];
        }
        __syncthreads();
        #pragma unroll
        for (int k = 0; k < 8; ++k) {
            int y = y0 + k * 8;
            dst[(tj * 64 + y) * 512 + ti * 64 + x] = tile[x][y];
        }
    }
}

__global__ __launch_bounds__(512) void k_edt(float* __restrict__ bufA,
                                             float* __restrict__ bufB,
                                             float* __restrict__ minmax)
{
    __shared__ float sbuf[2][514];
    __shared__ float tile[64][65];
    __shared__ float rmn[8], rmx[8];

    int m = blockIdx.x;
    float* A = bufA + (long)m * 262144;
    float* B = bufB + (long)m * 262144;

    // iter 1: rows, then cols (via transpose)
    sweep_down(A, sbuf);  sweep_up(A, sbuf);
    transpose512(A, B, tile); __syncthreads();
    sweep_down(B, sbuf);  sweep_up(B, sbuf);
    transpose512(B, A, tile); __syncthreads();
    // iter 2
    sweep_down(A, sbuf);  sweep_up(A, sbuf);
    transpose512(A, B, tile); __syncthreads();
    sweep_down(B, sbuf);  sweep_up(B, sbuf);
    // final result lives in B, transposed orientation (consistent for all maps
    // -> window pairing & per-window sort & min/max are invariant)

    // min/max reduction over B
    int t = threadIdx.x;
    float mn = BIGF, mx = -BIGF;
    for (int i = t; i < 262144; i += 512) {
        float v = B[i];
        mn = fminf(mn, v); mx = fmaxf(mx, v);
    }
    for (int o = 32; o > 0; o >>= 1) {
        mn = fminf(mn, __shfl_down(mn, o));
        mx = fmaxf(mx, __shfl_down(mx, o));
    }
    if ((t & 63) == 0) { rmn[t >> 6] = mn; rmx[t >> 6] = mx; }
    __syncthreads();
    if (t == 0) {
        for (int i = 1; i < 8; ++i) { mn = fminf(mn, rmn[i]); mx = fmaxf(mx, rmx[i]); }
        minmax[2 * m] = mn; minmax[2 * m + 1] = mx;
    }
}

// ---------------------------------------------------------------------------
// K3: per-window normalize + bitonic sort (p and t) + MSE partial sum
// ---------------------------------------------------------------------------
__global__ __launch_bounds__(256) void k_loss(const float* __restrict__ bufB,
                                              const float* __restrict__ minmax,
                                              float* __restrict__ acc)
{
    __shared__ float sp[4096];
    __shared__ float st[4096];
    __shared__ float rs[4];

    int t = threadIdx.x;
    int w = blockIdx.x & 63, b = blockIdx.x >> 6;
    int wi = w >> 3, wj = w & 7;

    const float* P = bufB + (long)b * 262144;
    const float* T = bufB + (long)(16 + b) * 262144;
    float mnP = minmax[2 * b],        mxP = minmax[2 * b + 1];
    float mnT = minmax[2 * (16 + b)], mxT = minmax[2 * (16 + b) + 1];
    float sclP = 1.0f / (mxP - mnP + 1e-6f);
    float sclT = 1.0f / (mxT - mnT + 1e-6f);

    for (int i = t; i < 4096; i += 256) {
        int y = wi * 64 + (i >> 6), x = wj * 64 + (i & 63);
        sp[i] = (P[y * 512 + x] - mnP) * sclP;
        st[i] = (T[y * 512 + x] - mnT) * sclT;
    }
    __syncthreads();

    for (int k = 2; k <= 4096; k <<= 1) {
        for (int j = k >> 1; j > 0; j >>= 1) {
            for (int i = t; i < 4096; i += 256) {
                int ixj = i ^ j;
                if (ixj > i) {
                    bool up = (i & k) == 0;
                    float a = sp[i], c = sp[ixj];
                    if ((a > c) == up) { sp[i] = c; sp[ixj] = a; }
                    float e = st[i], f = st[ixj];
                    if ((e > f) == up) { st[i] = f; st[ixj] = e; }
                }
            }
            __syncthreads();
        }
    }

    float s = 0.0f;
    for (int i = t; i < 4096; i += 256) { float d = sp[i] - st[i]; s += d * d; }
    for (int o = 32; o > 0; o >>= 1) s += __shfl_down(s, o);
    if ((t & 63) == 0) rs[t >> 6] = s;
    __syncthreads();
    if (t == 0) atomicAdd(acc, rs[0] + rs[1] + rs[2] + rs[3]);
}

// ---------------------------------------------------------------------------
// K4: finalize
// ---------------------------------------------------------------------------
__global__ void k_final(const float* __restrict__ acc, float* __restrict__ out)
{
    float mean = *acc * (1.0f / 4194304.0f);   // / (16 * 64 * 4096)
    out[0] = mean * 0.005f;
    out[1] = mean;
}

extern "C" void kernel_launch(void* const* d_in, const int* in_sizes, int n_in,
                              void* d_out, int out_size, void* d_ws, size_t ws_size,
                              hipStream_t stream)
{
    const float* pred = (const float*)d_in[0];
    const float* tgt  = (const float*)d_in[1];
    float* out = (float*)d_out;

    char* ws = (char*)d_ws;
    float* bufA   = (float*)ws;                          // 32 MB: 32 maps
    float* bufB   = (float*)(ws + (32ull << 20));        // 32 MB: transpose/pingpong
    float* minmax = (float*)(ws + (64ull << 20));        // 64 floats
    float* acc    = minmax + 64;                         // 1 float

    k_init <<<16 * 1024, 256, 0, stream>>>(pred, tgt, bufA, acc);
    k_edt  <<<32,        512, 0, stream>>>(bufA, bufB, minmax);
    k_loss <<<1024,      256, 0, stream>>>(bufB, minmax, acc);
    k_final<<<1,         1,   0, stream>>>(acc, out);
}

// Round 2
// 894.469 us; speedup vs baseline: 1.4026x; 1.4026x over previous
//
#include <hip/hip_runtime.h>

#define BIGF 1e20f
#define VF   1e10f

constexpr float SQ2 = 1.41421356237309515f;  // fp32 0x3FB504F3, == jnp.sqrt(2.0) in f32

// ---------------------------------------------------------------------------
// K1: binarize + channel max + dist init.  maps 0..15 = pred, 16..31 = target
// ---------------------------------------------------------------------------
__global__ __launch_bounds__(256) void k_init(const float* __restrict__ pred,
                                              const float* __restrict__ tgt,
                                              float* __restrict__ bufA,
                                              float* __restrict__ acc)
{
    if (blockIdx.x == 0 && threadIdx.x == 0) *acc = 0.0f;
    int idx = blockIdx.x * 256 + threadIdx.x;
    int b   = idx >> 18;
    int pix = idx & 262143;
    long base = (long)b * 3 * 262144 + pix;

    float p0 = pred[base], p1 = pred[base + 262144], p2 = pred[base + 2 * 262144];
    bool fgP = ((p0 + 1.0f) * 0.5f >= 0.7f) ||
               ((p1 + 1.0f) * 0.5f >= 0.7f) ||
               ((p2 + 1.0f) * 0.5f >= 0.7f);

    float t0 = tgt[base], t1 = tgt[base + 262144], t2 = tgt[base + 2 * 262144];
    float mt = fmaxf(fmaxf(t0, t1), t2);

    bufA[(long)b * 262144 + pix]        = fgP ? 0.0f : VF;
    bufA[(long)(16 + b) * 262144 + pix] = VF * (1.0f - mt);
}

// ---------------------------------------------------------------------------
// K2: barrier-free chamfer sweep. One WAVE (64 lanes) per map; lane owns 8 cols.
// ---------------------------------------------------------------------------
__device__ __forceinline__ void load_row8(const float* __restrict__ M, int r, int c0, float v[8])
{
    const float4* q = (const float4*)(M + ((long)r << 9) + c0);
    float4 a = q[0], b = q[1];
    v[0] = a.x; v[1] = a.y; v[2] = a.z; v[3] = a.w;
    v[4] = b.x; v[5] = b.y; v[6] = b.z; v[7] = b.w;
}

__device__ __forceinline__ void store_row8(float* __restrict__ M, int r, int c0, const float v[8])
{
    float4* q = (float4*)(M + ((long)r << 9) + c0);
    q[0] = make_float4(v[0], v[1], v[2], v[3]);
    q[1] = make_float4(v[4], v[5], v[6], v[7]);
}

// One row-step. SLOT is a compile-time prefetch slot so buf[] stays in VGPRs.
#define ROW_STEP(G, SLOT)                                                     \
    {                                                                         \
        const int r = start + (G) * DIR;                                      \
        float cur[8];                                                         \
        _Pragma("unroll")                                                     \
        for (int j = 0; j < 8; ++j) cur[j] = buf[SLOT][j];                    \
        int rp = r + 4 * DIR;                                                 \
        rp = rp < 0 ? 0 : (rp > 511 ? 511 : rp);                              \
        load_row8(M, rp, c0, buf[SLOT]);                                      \
        float left  = __shfl_up(p[7], 1);                                     \
        float right = __shfl_down(p[0], 1);                                   \
        if (lane == 0)  left  = BIGF;                                         \
        if (lane == 63) right = BIGF;                                         \
        float nv[8];                                                          \
        _Pragma("unroll")                                                     \
        for (int j = 0; j < 8; ++j) {                                         \
            float l  = (j == 0) ? left  : p[j - 1];                           \
            float rr = (j == 7) ? right : p[j + 1];                           \
            nv[j] = fminf(fminf(cur[j], p[j] + 1.0f), fminf(l, rr) + SQ2);    \
        }                                                                     \
        store_row8(M, r, c0, nv);                                             \
        _Pragma("unroll")                                                     \
        for (int j = 0; j < 8; ++j) {                                         \
            p[j] = nv[j];                                                     \
            if (TRACK) { mn = fminf(mn, nv[j]); mx = fmaxf(mx, nv[j]); }      \
        }                                                                     \
    }

template<int DIR, bool TRACK>
__device__ __forceinline__ void sweep_dir(float* __restrict__ M, int lane, int c0,
                                          float p[8], float& mn, float& mx)
{
    float buf[4][8];
    const int start = (DIR > 0) ? 1 : 510;
    load_row8(M, start + 0 * DIR, c0, buf[0]);
    load_row8(M, start + 1 * DIR, c0, buf[1]);
    load_row8(M, start + 2 * DIR, c0, buf[2]);
    load_row8(M, start + 3 * DIR, c0, buf[3]);
    for (int gg = 0; gg < 127; ++gg) {
        int g = gg * 4;
        ROW_STEP(g + 0, 0)
        ROW_STEP(g + 1, 1)
        ROW_STEP(g + 2, 2)
        ROW_STEP(g + 3, 3)
    }
    ROW_STEP(508, 0)
    ROW_STEP(509, 1)
    ROW_STEP(510, 2)
}

__global__ __launch_bounds__(64) void k_sweep(float* __restrict__ bufM,
                                              float* __restrict__ minmax,
                                              int final_pass)
{
    float* M = bufM + ((long)blockIdx.x << 18);
    const int lane = threadIdx.x;
    const int c0 = lane << 3;

    float p[8];
    load_row8(M, 0, c0, p);          // row 0 stays unchanged (reference semantics)
    float mn = BIGF, mx = -BIGF;

    sweep_dir<1, false>(M, lane, c0, p, mn, mx);   // down: p = new row 511
    __threadfence_block();                          // drain stores before up-sweep reads

    if (final_pass) {
        #pragma unroll
        for (int j = 0; j < 8; ++j) { mn = fminf(mn, p[j]); mx = fmaxf(mx, p[j]); }
        sweep_dir<-1, true>(M, lane, c0, p, mn, mx);
        for (int o = 32; o > 0; o >>= 1) {
            mn = fminf(mn, __shfl_down(mn, o));
            mx = fmaxf(mx, __shfl_down(mx, o));
        }
        if (lane == 0) { minmax[2 * blockIdx.x] = mn; minmax[2 * blockIdx.x + 1] = mx; }
    } else {
        sweep_dir<-1, false>(M, lane, c0, p, mn, mx);
    }
}

// ---------------------------------------------------------------------------
// K3: transpose, 64x64 tiles, fully parallel (32 maps x 64 tiles blocks)
// ---------------------------------------------------------------------------
__global__ __launch_bounds__(256) void k_transpose(const float* __restrict__ src,
                                                   float* __restrict__ dst)
{
    __shared__ float tile[64][65];
    int m    = blockIdx.x >> 6;
    int tidx = blockIdx.x & 63;
    int ti = tidx >> 3, tj = tidx & 7;
    const float* S = src + ((long)m << 18);
    float*       D = dst + ((long)m << 18);
    int x = threadIdx.x & 63, y0 = threadIdx.x >> 6;   // y0 in 0..3
    #pragma unroll
    for (int k = 0; k < 16; ++k) {
        int y = y0 + (k << 2);
        tile[y][x] = S[(ti * 64 + y) * 512 + tj * 64 + x];
    }
    __syncthreads();
    #pragma unroll
    for (int k = 0; k < 16; ++k) {
        int y = y0 + (k << 2);
        D[(tj * 64 + y) * 512 + ti * 64 + x] = tile[x][y];
    }
}

// ---------------------------------------------------------------------------
// K4: per-window normalize + bitonic sort (p and t) + MSE partial sum
// ---------------------------------------------------------------------------
__global__ __launch_bounds__(512) void k_loss(const float* __restrict__ bufB,
                                              const float* __restrict__ minmax,
                                              float* __restrict__ acc)
{
    __shared__ float sp[4096];
    __shared__ float st[4096];
    __shared__ float rs[8];

    int t = threadIdx.x;
    int w = blockIdx.x & 63, b = blockIdx.x >> 6;
    int wi = w >> 3, wj = w & 7;

    const float* P = bufB + (long)b * 262144;
    const float* T = bufB + (long)(16 + b) * 262144;
    float mnP = minmax[2 * b],        mxP = minmax[2 * b + 1];
    float mnT = minmax[2 * (16 + b)], mxT = minmax[2 * (16 + b) + 1];
    float sclP = 1.0f / (mxP - mnP + 1e-6f);
    float sclT = 1.0f / (mxT - mnT + 1e-6f);

    for (int i = t; i < 4096; i += 512) {
        int y = wi * 64 + (i >> 6), x = wj * 64 + (i & 63);
        sp[i] = (P[y * 512 + x] - mnP) * sclP;
        st[i] = (T[y * 512 + x] - mnT) * sclT;
    }
    __syncthreads();

    for (int k = 2; k <= 4096; k <<= 1) {
        for (int j = k >> 1; j > 0; j >>= 1) {
            #pragma unroll 1
            for (int q = t; q < 2048; q += 512) {
                int i   = ((q & ~(j - 1)) << 1) | (q & (j - 1));
                int ixj = i | j;
                bool up = (i & k) == 0;
                float a = sp[i], c = sp[ixj];
                if ((a > c) == up) { sp[i] = c; sp[ixj] = a; }
                float e = st[i], f = st[ixj];
                if ((e > f) == up) { st[i] = f; st[ixj] = e; }
            }
            __syncthreads();
        }
    }

    float s = 0.0f;
    for (int i = t; i < 4096; i += 512) { float d = sp[i] - st[i]; s += d * d; }
    for (int o = 32; o > 0; o >>= 1) s += __shfl_down(s, o);
    if ((t & 63) == 0) rs[t >> 6] = s;
    __syncthreads();
    if (t == 0) {
        float tot = 0.0f;
        #pragma unroll
        for (int i = 0; i < 8; ++i) tot += rs[i];
        atomicAdd(acc, tot);
    }
}

// ---------------------------------------------------------------------------
// K5: finalize
// ---------------------------------------------------------------------------
__global__ void k_final(const float* __restrict__ acc, float* __restrict__ out)
{
    float mean = *acc * (1.0f / 4194304.0f);
    out[0] = mean * 0.005f;
    out[1] = mean;
}

extern "C" void kernel_launch(void* const* d_in, const int* in_sizes, int n_in,
                              void* d_out, int out_size, void* d_ws, size_t ws_size,
                              hipStream_t stream)
{
    const float* pred = (const float*)d_in[0];
    const float* tgt  = (const float*)d_in[1];
    float* out = (float*)d_out;

    char* ws = (char*)d_ws;
    float* bufA   = (float*)ws;                     // 32 MB
    float* bufB   = (float*)(ws + (32ull << 20));   // 32 MB
    float* minmax = (float*)(ws + (64ull << 20));   // 64 floats
    float* acc    = minmax + 64;

    k_init     <<<16 * 1024, 256, 0, stream>>>(pred, tgt, bufA, acc);
    k_sweep    <<<32,  64,  0, stream>>>(bufA, minmax, 0);   // rows, iter 1
    k_transpose<<<2048, 256, 0, stream>>>(bufA, bufB);
    k_sweep    <<<32,  64,  0, stream>>>(bufB, minmax, 0);   // cols, iter 1
    k_transpose<<<2048, 256, 0, stream>>>(bufB, bufA);
    k_sweep    <<<32,  64,  0, stream>>>(bufA, minmax, 0);   // rows, iter 2
    k_transpose<<<2048, 256, 0, stream>>>(bufA, bufB);
    k_sweep    <<<32,  64,  0, stream>>>(bufB, minmax, 1);   // cols, iter 2 + minmax
    k_loss     <<<1024, 512, 0, stream>>>(bufB, minmax, acc);
    k_final    <<<1, 1, 0, stream>>>(acc, out);
}

// Round 3
// 853.840 us; speedup vs baseline: 1.4694x; 1.0476x over previous
//
#include <hip/hip_runtime.h>

#define BIGF 1e20f
#define VF   1e10f

constexpr float SQ2 = 1.41421356237309515f;  // fp32 0x3FB504F3, == jnp.sqrt(2.0) in f32

// ---------------------------------------------------------------------------
// DPP wave shifts: VALU-latency cross-lane neighbor exchange.
//   shr1: lane i <- lane i-1 (lane 0 -> old=BIGF)   [left neighbor]
//   shl1: lane i <- lane i+1 (lane 63 -> old=BIGF)  [right neighbor]
// bound_ctrl=false => invalid lanes keep `old`.
// ---------------------------------------------------------------------------
__device__ __forceinline__ float dpp_left(float x)
{
    int o = __builtin_amdgcn_update_dpp(0x60AD78ECu /*1e20f bits*/, __float_as_int(x),
                                        0x138, 0xF, 0xF, false);   // WAVE_SHR1
    return __int_as_float(o);
}
__device__ __forceinline__ float dpp_right(float x)
{
    int o = __builtin_amdgcn_update_dpp(0x60AD78ECu /*1e20f bits*/, __float_as_int(x),
                                        0x130, 0xF, 0xF, false);   // WAVE_SHL1
    return __int_as_float(o);
}

// ---------------------------------------------------------------------------
// K1: binarize + channel max + dist init.  maps 0..15 = pred, 16..31 = target
// ---------------------------------------------------------------------------
__global__ __launch_bounds__(256) void k_init(const float* __restrict__ pred,
                                              const float* __restrict__ tgt,
                                              float* __restrict__ bufA,
                                              float* __restrict__ acc)
{
    if (blockIdx.x == 0 && threadIdx.x == 0) *acc = 0.0f;
    int idx = blockIdx.x * 256 + threadIdx.x;
    int b   = idx >> 18;
    int pix = idx & 262143;
    long base = (long)b * 3 * 262144 + pix;

    float p0 = pred[base], p1 = pred[base + 262144], p2 = pred[base + 2 * 262144];
    bool fgP = ((p0 + 1.0f) * 0.5f >= 0.7f) ||
               ((p1 + 1.0f) * 0.5f >= 0.7f) ||
               ((p2 + 1.0f) * 0.5f >= 0.7f);

    float t0 = tgt[base], t1 = tgt[base + 262144], t2 = tgt[base + 2 * 262144];
    float mt = fmaxf(fmaxf(t0, t1), t2);

    bufA[(long)b * 262144 + pix]        = fgP ? 0.0f : VF;
    bufA[(long)(16 + b) * 262144 + pix] = VF * (1.0f - mt);
}

// ---------------------------------------------------------------------------
// K2: barrier-free chamfer sweep. One WAVE (64 lanes) per map; lane owns 8 cols.
// Cross-lane via DPP (no LDS latency on the row-to-row critical path).
// ---------------------------------------------------------------------------
__device__ __forceinline__ void load_row8(const float* __restrict__ M, int r, int c0, float v[8])
{
    const float4* q = (const float4*)(M + ((long)r << 9) + c0);
    float4 a = q[0], b = q[1];
    v[0] = a.x; v[1] = a.y; v[2] = a.z; v[3] = a.w;
    v[4] = b.x; v[5] = b.y; v[6] = b.z; v[7] = b.w;
}

__device__ __forceinline__ void store_row8(float* __restrict__ M, int r, int c0, const float v[8])
{
    float4* q = (float4*)(M + ((long)r << 9) + c0);
    q[0] = make_float4(v[0], v[1], v[2], v[3]);
    q[1] = make_float4(v[4], v[5], v[6], v[7]);
}

#define ROW_STEP(G, SLOT)                                                     \
    {                                                                         \
        const int r = start + (G) * DIR;                                      \
        float cur[8];                                                         \
        _Pragma("unroll")                                                     \
        for (int j = 0; j < 8; ++j) cur[j] = buf[SLOT][j];                    \
        int rp = r + 4 * DIR;                                                 \
        rp = rp < 0 ? 0 : (rp > 511 ? 511 : rp);                              \
        load_row8(M, rp, c0, buf[SLOT]);                                      \
        float left  = dpp_left(p[7]);                                         \
        float right = dpp_right(p[0]);                                        \
        float nv[8];                                                          \
        _Pragma("unroll")                                                     \
        for (int j = 0; j < 8; ++j) {                                         \
            float l  = (j == 0) ? left  : p[j - 1];                           \
            float rr = (j == 7) ? right : p[j + 1];                           \
            nv[j] = fminf(fminf(cur[j], p[j] + 1.0f), fminf(l, rr) + SQ2);    \
        }                                                                     \
        store_row8(M, r, c0, nv);                                             \
        _Pragma("unroll")                                                     \
        for (int j = 0; j < 8; ++j) {                                         \
            p[j] = nv[j];                                                     \
            if (TRACK) { mn = fminf(mn, nv[j]); mx = fmaxf(mx, nv[j]); }      \
        }                                                                     \
    }

template<int DIR, bool TRACK>
__device__ __forceinline__ void sweep_dir(float* __restrict__ M, int lane, int c0,
                                          float p[8], float& mn, float& mx)
{
    float buf[4][8];
    const int start = (DIR > 0) ? 1 : 510;
    load_row8(M, start + 0 * DIR, c0, buf[0]);
    load_row8(M, start + 1 * DIR, c0, buf[1]);
    load_row8(M, start + 2 * DIR, c0, buf[2]);
    load_row8(M, start + 3 * DIR, c0, buf[3]);
    for (int gg = 0; gg < 127; ++gg) {
        int g = gg * 4;
        ROW_STEP(g + 0, 0)
        ROW_STEP(g + 1, 1)
        ROW_STEP(g + 2, 2)
        ROW_STEP(g + 3, 3)
    }
    ROW_STEP(508, 0)
    ROW_STEP(509, 1)
    ROW_STEP(510, 2)
}

__global__ __launch_bounds__(64) void k_sweep(float* __restrict__ bufM,
                                              float* __restrict__ minmax,
                                              int final_pass)
{
    float* M = bufM + ((long)blockIdx.x << 18);
    const int lane = threadIdx.x;
    const int c0 = lane << 3;

    float p[8];
    load_row8(M, 0, c0, p);          // row 0 stays unchanged (reference semantics)
    float mn = BIGF, mx = -BIGF;

    sweep_dir<1, false>(M, lane, c0, p, mn, mx);   // down: p = new row 511
    __threadfence_block();

    if (final_pass) {
        #pragma unroll
        for (int j = 0; j < 8; ++j) { mn = fminf(mn, p[j]); mx = fmaxf(mx, p[j]); }
        sweep_dir<-1, true>(M, lane, c0, p, mn, mx);
        for (int o = 32; o > 0; o >>= 1) {
            mn = fminf(mn, __shfl_down(mn, o));
            mx = fmaxf(mx, __shfl_down(mx, o));
        }
        if (lane == 0) { minmax[2 * blockIdx.x] = mn; minmax[2 * blockIdx.x + 1] = mx; }
    } else {
        sweep_dir<-1, false>(M, lane, c0, p, mn, mx);
    }
}

// ---------------------------------------------------------------------------
// K3: transpose, 64x64 tiles, fully parallel (32 maps x 64 tiles blocks)
// ---------------------------------------------------------------------------
__global__ __launch_bounds__(256) void k_transpose(const float* __restrict__ src,
                                                   float* __restrict__ dst)
{
    __shared__ float tile[64][65];
    int m    = blockIdx.x >> 6;
    int tidx = blockIdx.x & 63;
    int ti = tidx >> 3, tj = tidx & 7;
    const float* S = src + ((long)m << 18);
    float*       D = dst + ((long)m << 18);
    int x = threadIdx.x & 63, y0 = threadIdx.x >> 6;
    #pragma unroll
    for (int k = 0; k < 16; ++k) {
        int y = y0 + (k << 2);
        tile[y][x] = S[(ti * 64 + y) * 512 + tj * 64 + x];
    }
    __syncthreads();
    #pragma unroll
    for (int k = 0; k < 16; ++k) {
        int y = y0 + (k << 2);
        D[(tj * 64 + y) * 512 + ti * 64 + x] = tile[x][y];
    }
}

// ---------------------------------------------------------------------------
// K4: per-window normalize + bitonic sort (p and t) + MSE partial sum
// ---------------------------------------------------------------------------
__global__ __launch_bounds__(512) void k_loss(const float* __restrict__ bufB,
                                              const float* __restrict__ minmax,
                                              float* __restrict__ acc)
{
    __shared__ float sp[4096];
    __shared__ float st[4096];
    __shared__ float rs[8];

    int t = threadIdx.x;
    int w = blockIdx.x & 63, b = blockIdx.x >> 6;
    int wi = w >> 3, wj = w & 7;

    const float* P = bufB + (long)b * 262144;
    const float* T = bufB + (long)(16 + b) * 262144;
    float mnP = minmax[2 * b],        mxP = minmax[2 * b + 1];
    float mnT = minmax[2 * (16 + b)], mxT = minmax[2 * (16 + b) + 1];
    float sclP = 1.0f / (mxP - mnP + 1e-6f);
    float sclT = 1.0f / (mxT - mnT + 1e-6f);

    for (int i = t; i < 4096; i += 512) {
        int y = wi * 64 + (i >> 6), x = wj * 64 + (i & 63);
        sp[i] = (P[y * 512 + x] - mnP) * sclP;
        st[i] = (T[y * 512 + x] - mnT) * sclT;
    }
    __syncthreads();

    for (int k = 2; k <= 4096; k <<= 1) {
        for (int j = k >> 1; j > 0; j >>= 1) {
            #pragma unroll 1
            for (int q = t; q < 2048; q += 512) {
                int i   = ((q & ~(j - 1)) << 1) | (q & (j - 1));
                int ixj = i | j;
                bool up = (i & k) == 0;
                float a = sp[i], c = sp[ixj];
                if ((a > c) == up) { sp[i] = c; sp[ixj] = a; }
                float e = st[i], f = st[ixj];
                if ((e > f) == up) { st[i] = f; st[ixj] = e; }
            }
            __syncthreads();
        }
    }

    float s = 0.0f;
    for (int i = t; i < 4096; i += 512) { float d = sp[i] - st[i]; s += d * d; }
    for (int o = 32; o > 0; o >>= 1) s += __shfl_down(s, o);
    if ((t & 63) == 0) rs[t >> 6] = s;
    __syncthreads();
    if (t == 0) {
        float tot = 0.0f;
        #pragma unroll
        for (int i = 0; i < 8; ++i) tot += rs[i];
        atomicAdd(acc, tot);
    }
}

// ---------------------------------------------------------------------------
// K5: finalize
// ---------------------------------------------------------------------------
__global__ void k_final(const float* __restrict__ acc, float* __restrict__ out)
{
    float mean = *acc * (1.0f / 4194304.0f);
    out[0] = mean * 0.005f;
    out[1] = mean;
}

extern "C" void kernel_launch(void* const* d_in, const int* in_sizes, int n_in,
                              void* d_out, int out_size, void* d_ws, size_t ws_size,
                              hipStream_t stream)
{
    const float* pred = (const float*)d_in[0];
    const float* tgt  = (const float*)d_in[1];
    float* out = (float*)d_out;

    char* ws = (char*)d_ws;
    float* bufA   = (float*)ws;                     // 32 MB
    float* bufB   = (float*)(ws + (32ull << 20));   // 32 MB
    float* minmax = (float*)(ws + (64ull << 20));   // 64 floats
    float* acc    = minmax + 64;

    k_init     <<<16 * 1024, 256, 0, stream>>>(pred, tgt, bufA, acc);
    k_sweep    <<<32,  64,  0, stream>>>(bufA, minmax, 0);   // rows, iter 1
    k_transpose<<<2048, 256, 0, stream>>>(bufA, bufB);
    k_sweep    <<<32,  64,  0, stream>>>(bufB, minmax, 0);   // cols, iter 1
    k_transpose<<<2048, 256, 0, stream>>>(bufB, bufA);
    k_sweep    <<<32,  64,  0, stream>>>(bufA, minmax, 0);   // rows, iter 2
    k_transpose<<<2048, 256, 0, stream>>>(bufA, bufB);
    k_sweep    <<<32,  64,  0, stream>>>(bufB, minmax, 1);   // cols, iter 2 + minmax
    k_loss     <<<1024, 512, 0, stream>>>(bufB, minmax, acc);
    k_final    <<<1, 1, 0, stream>>>(acc, out);
}

// Round 4
// 786.393 us; speedup vs baseline: 1.5954x; 1.0858x over previous
//
#include <hip/hip_runtime.h>

#define BIGF 1e20f
#define VF   1e10f

constexpr float SQ2 = 1.41421356237309515f;  // fp32 0x3FB504F3, == jnp.sqrt(2.0) in f32

// XCD affinity: block->XCD assumed blockIdx%8 (round-robin, measured heuristic).
// Every kernel maps blocks so that all blocks touching map m have blockIdx%8==m%8.
// Then each XCD's 4MB L2 holds its 4 maps (4 x 1MB) resident across the pipeline.

// ---------------------------------------------------------------------------
// DPP wave shifts: VALU-latency cross-lane neighbor exchange.
// ---------------------------------------------------------------------------
__device__ __forceinline__ float dpp_left(float x)
{
    int o = __builtin_amdgcn_update_dpp(0x60AD78ECu /*1e20f*/, __float_as_int(x),
                                        0x138, 0xF, 0xF, false);   // WAVE_SHR1
    return __int_as_float(o);
}
__device__ __forceinline__ float dpp_right(float x)
{
    int o = __builtin_amdgcn_update_dpp(0x60AD78ECu /*1e20f*/, __float_as_int(x),
                                        0x130, 0xF, 0xF, false);   // WAVE_SHL1
    return __int_as_float(o);
}

// ---------------------------------------------------------------------------
// K1: binarize + channel max + dist init.  maps 0..15 = pred, 16..31 = target
// Affinity: blocks with blockIdx%8 == r handle item b in {r, r+8} (and b+16:
// (b+16)%8 == b%8, same XCD).
// ---------------------------------------------------------------------------
__global__ __launch_bounds__(256) void k_init(const float* __restrict__ pred,
                                              const float* __restrict__ tgt,
                                              float* __restrict__ bufA,
                                              float* __restrict__ acc,
                                              unsigned* __restrict__ count)
{
    if (blockIdx.x == 0 && threadIdx.x == 0) { *acc = 0.0f; *count = 0u; }
    int r = blockIdx.x & 7;
    int k = blockIdx.x >> 3;            // 0..2047
    int b = r + 8 * (k >> 10);          // item 0..15
    int pix = (k & 1023) * 256 + threadIdx.x;
    long base = (long)b * 3 * 262144 + pix;

    float p0 = pred[base], p1 = pred[base + 262144], p2 = pred[base + 2 * 262144];
    bool fgP = ((p0 + 1.0f) * 0.5f >= 0.7f) ||
               ((p1 + 1.0f) * 0.5f >= 0.7f) ||
               ((p2 + 1.0f) * 0.5f >= 0.7f);

    float t0 = tgt[base], t1 = tgt[base + 262144], t2 = tgt[base + 2 * 262144];
    float mt = fmaxf(fmaxf(t0, t1), t2);

    bufA[(long)b * 262144 + pix]        = fgP ? 0.0f : VF;
    bufA[(long)(16 + b) * 262144 + pix] = VF * (1.0f - mt);
}

// ---------------------------------------------------------------------------
// K2: barrier-free chamfer sweep. One WAVE per map (blockIdx==map, %8 affine).
// Lane owns 8 cols; DPP for cross-lane; depth-8 register prefetch pipeline.
// ---------------------------------------------------------------------------
__device__ __forceinline__ void load_row8(const float* __restrict__ M, int r, int c0, float v[8])
{
    const float4* q = (const float4*)(M + ((long)r << 9) + c0);
    float4 a = q[0], b = q[1];
    v[0] = a.x; v[1] = a.y; v[2] = a.z; v[3] = a.w;
    v[4] = b.x; v[5] = b.y; v[6] = b.z; v[7] = b.w;
}

__device__ __forceinline__ void store_row8(float* __restrict__ M, int r, int c0, const float v[8])
{
    float4* q = (float4*)(M + ((long)r << 9) + c0);
    q[0] = make_float4(v[0], v[1], v[2], v[3]);
    q[1] = make_float4(v[4], v[5], v[6], v[7]);
}

#define ROW_STEP(G, SLOT)                                                     \
    {                                                                         \
        const int r = start + (G) * DIR;                                      \
        float cur[8];                                                         \
        _Pragma("unroll")                                                     \
        for (int j = 0; j < 8; ++j) cur[j] = buf[SLOT][j];                    \
        int rp = r + 8 * DIR;                                                 \
        rp = rp < 0 ? 0 : (rp > 511 ? 511 : rp);                              \
        load_row8(M, rp, c0, buf[SLOT]);                                      \
        float left  = dpp_left(p[7]);                                         \
        float right = dpp_right(p[0]);                                        \
        float nv[8];                                                          \
        _Pragma("unroll")                                                     \
        for (int j = 0; j < 8; ++j) {                                         \
            float l  = (j == 0) ? left  : p[j - 1];                           \
            float rr = (j == 7) ? right : p[j + 1];                           \
            nv[j] = fminf(fminf(cur[j], p[j] + 1.0f), fminf(l, rr) + SQ2);    \
        }                                                                     \
        store_row8(M, r, c0, nv);                                             \
        _Pragma("unroll")                                                     \
        for (int j = 0; j < 8; ++j) {                                         \
            p[j] = nv[j];                                                     \
            if (TRACK) { mn = fminf(mn, nv[j]); mx = fmaxf(mx, nv[j]); }      \
        }                                                                     \
    }

template<int DIR, bool TRACK>
__device__ __forceinline__ void sweep_dir(float* __restrict__ M, int lane, int c0,
                                          float p[8], float& mn, float& mx)
{
    float buf[8][8];
    const int start = (DIR > 0) ? 1 : 510;
    #pragma unroll
    for (int s = 0; s < 8; ++s) load_row8(M, start + s * DIR, c0, buf[s]);
    for (int gg = 0; gg < 63; ++gg) {
        int g = gg * 8;
        ROW_STEP(g + 0, 0)
        ROW_STEP(g + 1, 1)
        ROW_STEP(g + 2, 2)
        ROW_STEP(g + 3, 3)
        ROW_STEP(g + 4, 4)
        ROW_STEP(g + 5, 5)
        ROW_STEP(g + 6, 6)
        ROW_STEP(g + 7, 7)
    }
    ROW_STEP(504, 0)
    ROW_STEP(505, 1)
    ROW_STEP(506, 2)
    ROW_STEP(507, 3)
    ROW_STEP(508, 4)
    ROW_STEP(509, 5)
    ROW_STEP(510, 6)
}

__global__ __launch_bounds__(64) void k_sweep(float* __restrict__ bufM,
                                              float* __restrict__ minmax,
                                              int final_pass)
{
    float* M = bufM + ((long)blockIdx.x << 18);
    const int lane = threadIdx.x;
    const int c0 = lane << 3;

    float p[8];
    load_row8(M, 0, c0, p);          // row 0 stays unchanged (reference semantics)
    float mn = BIGF, mx = -BIGF;

    sweep_dir<1, false>(M, lane, c0, p, mn, mx);   // down: p = new row 511
    __threadfence_block();

    if (final_pass) {
        #pragma unroll
        for (int j = 0; j < 8; ++j) { mn = fminf(mn, p[j]); mx = fmaxf(mx, p[j]); }
        sweep_dir<-1, true>(M, lane, c0, p, mn, mx);
        for (int o = 32; o > 0; o >>= 1) {
            mn = fminf(mn, __shfl_down(mn, o));
            mx = fmaxf(mx, __shfl_down(mx, o));
        }
        if (lane == 0) { minmax[2 * blockIdx.x] = mn; minmax[2 * blockIdx.x + 1] = mx; }
    } else {
        sweep_dir<-1, false>(M, lane, c0, p, mn, mx);
    }
}

// ---------------------------------------------------------------------------
// K3: transpose, 64x64 tiles.  Affinity: map m = (blockIdx%8) + 8*((blockIdx>>3)>>6).
// ---------------------------------------------------------------------------
__global__ __launch_bounds__(256) void k_transpose(const float* __restrict__ src,
                                                   float* __restrict__ dst)
{
    __shared__ float tile[64][65];
    int r = blockIdx.x & 7;
    int k = blockIdx.x >> 3;            // 0..255
    int m = r + 8 * (k >> 6);           // map 0..31
    int tidx = k & 63;
    int ti = tidx >> 3, tj = tidx & 7;
    const float* S = src + ((long)m << 18);
    float*       D = dst + ((long)m << 18);
    int x = threadIdx.x & 63, y0 = threadIdx.x >> 6;
    #pragma unroll
    for (int kk = 0; kk < 16; ++kk) {
        int y = y0 + (kk << 2);
        tile[y][x] = S[(ti * 64 + y) * 512 + tj * 64 + x];
    }
    __syncthreads();
    #pragma unroll
    for (int kk = 0; kk < 16; ++kk) {
        int y = y0 + (kk << 2);
        D[(tj * 64 + y) * 512 + ti * 64 + x] = tile[x][y];
    }
}

// ---------------------------------------------------------------------------
// K4: per-window normalize + bitonic sort + MSE partial sum + fused finalize.
// Affinity: item b = (blockIdx%8) + 8*((blockIdx>>3)>>6); maps b and b+16 are
// both on XCD b%8.
// ---------------------------------------------------------------------------
__global__ __launch_bounds__(512) void k_loss(const float* __restrict__ bufB,
                                              const float* __restrict__ minmax,
                                              float* __restrict__ acc,
                                              unsigned* __restrict__ count,
                                              float* __restrict__ out)
{
    __shared__ float sp[4096];
    __shared__ float st[4096];
    __shared__ float rs[8];

    int t = threadIdx.x;
    int r = blockIdx.x & 7;
    int k = blockIdx.x >> 3;            // 0..127
    int b = r + 8 * (k >> 6);           // item 0..15
    int w = k & 63;
    int wi = w >> 3, wj = w & 7;

    const float* P = bufB + (long)b * 262144;
    const float* T = bufB + (long)(16 + b) * 262144;
    float mnP = minmax[2 * b],        mxP = minmax[2 * b + 1];
    float mnT = minmax[2 * (16 + b)], mxT = minmax[2 * (16 + b) + 1];
    float sclP = 1.0f / (mxP - mnP + 1e-6f);
    float sclT = 1.0f / (mxT - mnT + 1e-6f);

    for (int i = t; i < 4096; i += 512) {
        int y = wi * 64 + (i >> 6), x = wj * 64 + (i & 63);
        sp[i] = (P[y * 512 + x] - mnP) * sclP;
        st[i] = (T[y * 512 + x] - mnT) * sclT;
    }
    __syncthreads();

    for (int kk = 2; kk <= 4096; kk <<= 1) {
        for (int j = kk >> 1; j > 0; j >>= 1) {
            #pragma unroll 1
            for (int q = t; q < 2048; q += 512) {
                int i   = ((q & ~(j - 1)) << 1) | (q & (j - 1));
                int ixj = i | j;
                bool up = (i & kk) == 0;
                float a = sp[i], c = sp[ixj];
                if ((a > c) == up) { sp[i] = c; sp[ixj] = a; }
                float e = st[i], f = st[ixj];
                if ((e > f) == up) { st[i] = f; st[ixj] = e; }
            }
            __syncthreads();
        }
    }

    float s = 0.0f;
    for (int i = t; i < 4096; i += 512) { float d = sp[i] - st[i]; s += d * d; }
    for (int o = 32; o > 0; o >>= 1) s += __shfl_down(s, o);
    if ((t & 63) == 0) rs[t >> 6] = s;
    __syncthreads();
    if (t == 0) {
        float tot = 0.0f;
        #pragma unroll
        for (int i = 0; i < 8; ++i) tot += rs[i];
        atomicAdd(acc, tot);
        __threadfence();
        unsigned done = atomicAdd(count, 1u);
        if (done == 1023u) {
            float total = atomicAdd(acc, 0.0f);      // coherent read of final sum
            float mean = total * (1.0f / 4194304.0f);
            out[0] = mean * 0.005f;
            out[1] = mean;
        }
    }
}

extern "C" void kernel_launch(void* const* d_in, const int* in_sizes, int n_in,
                              void* d_out, int out_size, void* d_ws, size_t ws_size,
                              hipStream_t stream)
{
    const float* pred = (const float*)d_in[0];
    const float* tgt  = (const float*)d_in[1];
    float* out = (float*)d_out;

    char* ws = (char*)d_ws;
    float* bufA     = (float*)ws;                     // 32 MB
    float* bufB     = (float*)(ws + (32ull << 20));   // 32 MB
    float* minmax   = (float*)(ws + (64ull << 20));   // 64 floats
    float* acc      = minmax + 64;
    unsigned* count = (unsigned*)(acc + 1);

    k_init     <<<16 * 1024, 256, 0, stream>>>(pred, tgt, bufA, acc, count);
    k_sweep    <<<32,  64,  0, stream>>>(bufA, minmax, 0);   // rows, iter 1
    k_transpose<<<2048, 256, 0, stream>>>(bufA, bufB);
    k_sweep    <<<32,  64,  0, stream>>>(bufB, minmax, 0);   // cols, iter 1
    k_transpose<<<2048, 256, 0, stream>>>(bufB, bufA);
    k_sweep    <<<32,  64,  0, stream>>>(bufA, minmax, 0);   // rows, iter 2
    k_transpose<<<2048, 256, 0, stream>>>(bufA, bufB);
    k_sweep    <<<32,  64,  0, stream>>>(bufB, minmax, 1);   // cols, iter 2 + minmax
    k_loss     <<<1024, 512, 0, stream>>>(bufB, minmax, acc, count, out);
}

// Round 5
// 760.823 us; speedup vs baseline: 1.6490x; 1.0336x over previous
//
#include <hip/hip_runtime.h>

#define BIGF 1e20f
#define VF   1e10f

constexpr float SQ2 = 1.41421356237309515f;  // fp32 0x3FB504F3, == jnp.sqrt(2.0) in f32

// ---------------------------------------------------------------------------
// DPP wave shifts: VALU-latency cross-lane neighbor exchange.
// ---------------------------------------------------------------------------
__device__ __forceinline__ float dpp_left(float x)
{
    int o = __builtin_amdgcn_update_dpp(0x60AD78ECu /*1e20f*/, __float_as_int(x),
                                        0x138, 0xF, 0xF, false);   // WAVE_SHR1
    return __int_as_float(o);
}
__device__ __forceinline__ float dpp_right(float x)
{
    int o = __builtin_amdgcn_update_dpp(0x60AD78ECu /*1e20f*/, __float_as_int(x),
                                        0x130, 0xF, 0xF, false);   // WAVE_SHL1
    return __int_as_float(o);
}

// ---------------------------------------------------------------------------
// K1: binarize + channel max + dist init.  maps 0..15 = pred, 16..31 = target
// ---------------------------------------------------------------------------
__global__ __launch_bounds__(256) void k_init(const float* __restrict__ pred,
                                              const float* __restrict__ tgt,
                                              float* __restrict__ bufA,
                                              float* __restrict__ acc,
                                              unsigned* __restrict__ count)
{
    if (blockIdx.x == 0 && threadIdx.x == 0) { *acc = 0.0f; *count = 0u; }
    int r = blockIdx.x & 7;
    int k = blockIdx.x >> 3;
    int b = r + 8 * (k >> 10);
    int pix = (k & 1023) * 256 + threadIdx.x;
    long base = (long)b * 3 * 262144 + pix;

    float p0 = pred[base], p1 = pred[base + 262144], p2 = pred[base + 2 * 262144];
    bool fgP = ((p0 + 1.0f) * 0.5f >= 0.7f) ||
               ((p1 + 1.0f) * 0.5f >= 0.7f) ||
               ((p2 + 1.0f) * 0.5f >= 0.7f);

    float t0 = tgt[base], t1 = tgt[base + 262144], t2 = tgt[base + 2 * 262144];
    float mt = fmaxf(fmaxf(t0, t1), t2);

    bufA[(long)b * 262144 + pix]        = fgP ? 0.0f : VF;
    bufA[(long)(16 + b) * 262144 + pix] = VF * (1.0f - mt);
}

// ---------------------------------------------------------------------------
// K2: OUT-OF-PLACE chamfer sweep. One wave per map; lane owns 8 cols.
// Loads from S, stores to D (distinct restrict buffers) => compiler emits no
// store->load ordering waits in the row loop; loads pipeline depth-8.
// k_sweep(X, Y): down X->Y, up Y->X. Final result in X.
// ---------------------------------------------------------------------------
__device__ __forceinline__ void load_row8(const float* __restrict__ M, int r, int c0, float v[8])
{
    const float4* q = (const float4*)(M + ((long)r << 9) + c0);
    float4 a = q[0], b = q[1];
    v[0] = a.x; v[1] = a.y; v[2] = a.z; v[3] = a.w;
    v[4] = b.x; v[5] = b.y; v[6] = b.z; v[7] = b.w;
}

__device__ __forceinline__ void store_row8(float* __restrict__ M, int r, int c0, const float v[8])
{
    float4* q = (float4*)(M + ((long)r << 9) + c0);
    q[0] = make_float4(v[0], v[1], v[2], v[3]);
    q[1] = make_float4(v[4], v[5], v[6], v[7]);
}

#define ROW_STEP(G, SLOT)                                                     \
    {                                                                         \
        const int r = start + (G) * DIR;                                      \
        float cur[8];                                                         \
        _Pragma("unroll")                                                     \
        for (int j = 0; j < 8; ++j) cur[j] = buf[SLOT][j];                    \
        int rp = r + 8 * DIR;                                                 \
        rp = rp < 0 ? 0 : (rp > 511 ? 511 : rp);                              \
        load_row8(S, rp, c0, buf[SLOT]);                                      \
        float left  = dpp_left(p[7]);                                         \
        float right = dpp_right(p[0]);                                        \
        float nv[8];                                                          \
        _Pragma("unroll")                                                     \
        for (int j = 0; j < 8; ++j) {                                         \
            float l  = (j == 0) ? left  : p[j - 1];                           \
            float rr = (j == 7) ? right : p[j + 1];                           \
            nv[j] = fminf(fminf(cur[j], p[j] + 1.0f), fminf(l, rr) + SQ2);    \
        }                                                                     \
        store_row8(D, r, c0, nv);                                             \
        _Pragma("unroll")                                                     \
        for (int j = 0; j < 8; ++j) {                                         \
            p[j] = nv[j];                                                     \
            if (TRACK) { mn = fminf(mn, nv[j]); mx = fmaxf(mx, nv[j]); }      \
        }                                                                     \
    }

template<int DIR, bool TRACK>
__device__ __forceinline__ void sweep_dir(const float* __restrict__ S,
                                          float* __restrict__ D,
                                          int c0, float p[8], float& mn, float& mx)
{
    float buf[8][8];
    const int start = (DIR > 0) ? 1 : 510;
    #pragma unroll
    for (int s = 0; s < 8; ++s) load_row8(S, start + s * DIR, c0, buf[s]);
    for (int gg = 0; gg < 63; ++gg) {
        int g = gg * 8;
        ROW_STEP(g + 0, 0)
        ROW_STEP(g + 1, 1)
        ROW_STEP(g + 2, 2)
        ROW_STEP(g + 3, 3)
        ROW_STEP(g + 4, 4)
        ROW_STEP(g + 5, 5)
        ROW_STEP(g + 6, 6)
        ROW_STEP(g + 7, 7)
    }
    ROW_STEP(504, 0)
    ROW_STEP(505, 1)
    ROW_STEP(506, 2)
    ROW_STEP(507, 3)
    ROW_STEP(508, 4)
    ROW_STEP(509, 5)
    ROW_STEP(510, 6)
}

__global__ __launch_bounds__(64) void k_sweep(float* __restrict__ X0,
                                              float* __restrict__ Y0,
                                              float* __restrict__ minmax,
                                              int final_pass)
{
    float* X = X0 + ((long)blockIdx.x << 18);
    float* Y = Y0 + ((long)blockIdx.x << 18);
    const int c0 = (int)threadIdx.x << 3;

    float p[8];
    float mn = BIGF, mx = -BIGF;

    // down: X -> Y  (row 0 copied unchanged, reference semantics)
    load_row8(X, 0, c0, p);
    store_row8(Y, 0, c0, p);
    sweep_dir<1, false>(X, Y, c0, p, mn, mx);   // p = new row 511 (== Y[511])
    __threadfence_block();

    // up: Y -> X  (row 511 copied unchanged; p already holds it)
    store_row8(X, 511, c0, p);
    if (final_pass) {
        #pragma unroll
        for (int j = 0; j < 8; ++j) { mn = fminf(mn, p[j]); mx = fmaxf(mx, p[j]); }
        sweep_dir<-1, true>(Y, X, c0, p, mn, mx);
        for (int o = 32; o > 0; o >>= 1) {
            mn = fminf(mn, __shfl_down(mn, o));
            mx = fmaxf(mx, __shfl_down(mx, o));
        }
        if (threadIdx.x == 0) { minmax[2 * blockIdx.x] = mn; minmax[2 * blockIdx.x + 1] = mx; }
    } else {
        sweep_dir<-1, false>(Y, X, c0, p, mn, mx);
    }
}

// ---------------------------------------------------------------------------
// K3: transpose, 64x64 tiles.
// ---------------------------------------------------------------------------
__global__ __launch_bounds__(256) void k_transpose(const float* __restrict__ src,
                                                   float* __restrict__ dst)
{
    __shared__ float tile[64][65];
    int r = blockIdx.x & 7;
    int k = blockIdx.x >> 3;
    int m = r + 8 * (k >> 6);
    int tidx = k & 63;
    int ti = tidx >> 3, tj = tidx & 7;
    const float* S = src + ((long)m << 18);
    float*       D = dst + ((long)m << 18);
    int x = threadIdx.x & 63, y0 = threadIdx.x >> 6;
    #pragma unroll
    for (int kk = 0; kk < 16; ++kk) {
        int y = y0 + (kk << 2);
        tile[y][x] = S[(ti * 64 + y) * 512 + tj * 64 + x];
    }
    __syncthreads();
    #pragma unroll
    for (int kk = 0; kk < 16; ++kk) {
        int y = y0 + (kk << 2);
        D[(tj * 64 + y) * 512 + ti * 64 + x] = tile[x][y];
    }
}

// ---------------------------------------------------------------------------
// K4: register-blocked bitonic sort (8 elems/thread) + MSE + fused finalize.
// j<=4 in-register; 8<=j<=256 shfl_xor (no barrier); j>=512 via LDS (6 stages).
// ---------------------------------------------------------------------------
__device__ __forceinline__ void ce(float& a, float& b, bool up)
{
    float lo = fminf(a, b), hi = fmaxf(a, b);
    a = up ? lo : hi;
    b = up ? hi : lo;
}

__device__ __forceinline__ void merge8(float v[8], bool up)
{
    ce(v[0], v[4], up); ce(v[1], v[5], up); ce(v[2], v[6], up); ce(v[3], v[7], up);
    ce(v[0], v[2], up); ce(v[1], v[3], up); ce(v[4], v[6], up); ce(v[5], v[7], up);
    ce(v[0], v[1], up); ce(v[2], v[3], up); ce(v[4], v[5], up); ce(v[6], v[7], up);
}

__device__ __forceinline__ void sort8(float v[8], bool u8)
{
    // k=2
    ce(v[0], v[1], true);  ce(v[2], v[3], false);
    ce(v[4], v[5], true);  ce(v[6], v[7], false);
    // k=4
    ce(v[0], v[2], true);  ce(v[1], v[3], true);
    ce(v[4], v[6], false); ce(v[5], v[7], false);
    ce(v[0], v[1], true);  ce(v[2], v[3], true);
    ce(v[4], v[5], false); ce(v[6], v[7], false);
    // k=8
    merge8(v, u8);
}

__device__ __forceinline__ void xstage(float v[8], int j8, bool keepmin)
{
    #pragma unroll
    for (int e = 0; e < 8; ++e) {
        float o = __shfl_xor(v[e], j8);
        v[e] = keepmin ? fminf(v[e], o) : fmaxf(v[e], o);
    }
}

__device__ __forceinline__ void lstage2(float p[8], float q[8], int j8, bool keepmin,
                                        float* sp, float* st, int t)
{
    __syncthreads();
    float4* wp = (float4*)(sp + t * 8);
    float4* wq = (float4*)(st + t * 8);
    wp[0] = make_float4(p[0], p[1], p[2], p[3]);
    wp[1] = make_float4(p[4], p[5], p[6], p[7]);
    wq[0] = make_float4(q[0], q[1], q[2], q[3]);
    wq[1] = make_float4(q[4], q[5], q[6], q[7]);
    __syncthreads();
    int pt = t ^ j8;
    const float4* rp = (const float4*)(sp + pt * 8);
    const float4* rq = (const float4*)(st + pt * 8);
    float4 a = rp[0], bb = rp[1], c = rq[0], d = rq[1];
    float op[8] = {a.x, a.y, a.z, a.w, bb.x, bb.y, bb.z, bb.w};
    float oq[8] = {c.x, c.y, c.z, c.w, d.x, d.y, d.z, d.w};
    #pragma unroll
    for (int e = 0; e < 8; ++e) {
        p[e] = keepmin ? fminf(p[e], op[e]) : fmaxf(p[e], op[e]);
        q[e] = keepmin ? fminf(q[e], oq[e]) : fmaxf(q[e], oq[e]);
    }
}

__global__ __launch_bounds__(512) void k_loss(const float* __restrict__ bufB,
                                              const float* __restrict__ minmax,
                                              float* __restrict__ acc,
                                              unsigned* __restrict__ count,
                                              float* __restrict__ out)
{
    __shared__ float sp[4096];
    __shared__ float st[4096];
    __shared__ float rs[8];

    int t = threadIdx.x;
    int r = blockIdx.x & 7;
    int k = blockIdx.x >> 3;
    int b = r + 8 * (k >> 6);
    int w = k & 63;
    int wi = w >> 3, wj = w & 7;

    int i0 = t << 3;
    int y = wi * 64 + (i0 >> 6);
    int x = wj * 64 + (i0 & 63);

    float mnP = minmax[2 * b],        mxP = minmax[2 * b + 1];
    float mnT = minmax[2 * (16 + b)], mxT = minmax[2 * (16 + b) + 1];
    float sclP = 1.0f / (mxP - mnP + 1e-6f);
    float sclT = 1.0f / (mxT - mnT + 1e-6f);

    float p[8], q[8];
    {
        const float4* P4 = (const float4*)(bufB + (long)b * 262144 + y * 512 + x);
        const float4* T4 = (const float4*)(bufB + (long)(16 + b) * 262144 + y * 512 + x);
        float4 a = P4[0], bb = P4[1], c = T4[0], d = T4[1];
        p[0]=a.x; p[1]=a.y; p[2]=a.z; p[3]=a.w; p[4]=bb.x; p[5]=bb.y; p[6]=bb.z; p[7]=bb.w;
        q[0]=c.x; q[1]=c.y; q[2]=c.z; q[3]=c.w; q[4]=d.x;  q[5]=d.y;  q[6]=d.z;  q[7]=d.w;
        #pragma unroll
        for (int e = 0; e < 8; ++e) {
            p[e] = (p[e] - mnP) * sclP;
            q[e] = (q[e] - mnT) * sclT;
        }
    }

    bool u8 = ((t & 1) == 0);
    sort8(p, u8);
    sort8(q, u8);

    for (int kk = 16; kk <= 4096; kk <<= 1) {
        bool u = ((i0 & kk) == 0);
        for (int j = kk >> 1; j >= 8; j >>= 1) {
            bool l = ((i0 & j) == 0);
            bool keepmin = (u == l);
            int j8 = j >> 3;
            if (j8 < 64) {
                xstage(p, j8, keepmin);
                xstage(q, j8, keepmin);
            } else {
                lstage2(p, q, j8, keepmin, sp, st, t);
            }
        }
        merge8(p, u);
        merge8(q, u);
    }

    float s = 0.0f;
    #pragma unroll
    for (int e = 0; e < 8; ++e) { float d = p[e] - q[e]; s += d * d; }
    for (int o = 32; o > 0; o >>= 1) s += __shfl_down(s, o);
    if ((t & 63) == 0) rs[t >> 6] = s;
    __syncthreads();
    if (t == 0) {
        float tot = 0.0f;
        #pragma unroll
        for (int i = 0; i < 8; ++i) tot += rs[i];
        atomicAdd(acc, tot);
        __threadfence();
        unsigned done = atomicAdd(count, 1u);
        if (done == 1023u) {
            float total = atomicAdd(acc, 0.0f);
            float mean = total * (1.0f / 4194304.0f);
            out[0] = mean * 0.005f;
            out[1] = mean;
        }
    }
}

extern "C" void kernel_launch(void* const* d_in, const int* in_sizes, int n_in,
                              void* d_out, int out_size, void* d_ws, size_t ws_size,
                              hipStream_t stream)
{
    const float* pred = (const float*)d_in[0];
    const float* tgt  = (const float*)d_in[1];
    float* out = (float*)d_out;

    char* ws = (char*)d_ws;
    float* bufA     = (float*)ws;                     // 32 MB
    float* bufB     = (float*)(ws + (32ull << 20));   // 32 MB
    float* minmax   = (float*)(ws + (64ull << 20));   // 64 floats
    float* acc      = minmax + 64;
    unsigned* count = (unsigned*)(acc + 1);

    k_init     <<<16 * 1024, 256, 0, stream>>>(pred, tgt, bufA, acc, count);
    k_sweep    <<<32,  64,  0, stream>>>(bufA, bufB, minmax, 0);  // rows it1 -> A
    k_transpose<<<2048, 256, 0, stream>>>(bufA, bufB);            // A -> B
    k_sweep    <<<32,  64,  0, stream>>>(bufB, bufA, minmax, 0);  // cols it1 -> B
    k_transpose<<<2048, 256, 0, stream>>>(bufB, bufA);            // B -> A
    k_sweep    <<<32,  64,  0, stream>>>(bufA, bufB, minmax, 0);  // rows it2 -> A
    k_transpose<<<2048, 256, 0, stream>>>(bufA, bufB);            // A -> B
    k_sweep    <<<32,  64,  0, stream>>>(bufB, bufA, minmax, 1);  // cols it2 -> B (+minmax)
    k_loss     <<<1024, 512, 0, stream>>>(bufB, minmax, acc, count, out);
}

// Round 6
// 671.667 us; speedup vs baseline: 1.8679x; 1.1327x over previous
//
#include <hip/hip_runtime.h>

#define BIGF 1e20f
#define VF   1e10f

constexpr float SQ2 = 1.41421356237309515f;  // fp32 0x3FB504F3, == jnp.sqrt(2.0) in f32

// ---------------------------------------------------------------------------
// DPP wave shifts: VALU-latency cross-lane neighbor exchange.
// ---------------------------------------------------------------------------
__device__ __forceinline__ float dpp_left(float x)
{
    int o = __builtin_amdgcn_update_dpp(0x60AD78ECu /*1e20f*/, __float_as_int(x),
                                        0x138, 0xF, 0xF, false);   // WAVE_SHR1
    return __int_as_float(o);
}
__device__ __forceinline__ float dpp_right(float x)
{
    int o = __builtin_amdgcn_update_dpp(0x60AD78ECu /*1e20f*/, __float_as_int(x),
                                        0x130, 0xF, 0xF, false);   // WAVE_SHL1
    return __int_as_float(o);
}

// ---------------------------------------------------------------------------
// K1: binarize + channel max + dist init.  maps 0..15 = pred, 16..31 = target
// ---------------------------------------------------------------------------
__global__ __launch_bounds__(256) void k_init(const float* __restrict__ pred,
                                              const float* __restrict__ tgt,
                                              float* __restrict__ bufA,
                                              float* __restrict__ acc,
                                              unsigned* __restrict__ count)
{
    if (blockIdx.x == 0 && threadIdx.x == 0) { *acc = 0.0f; *count = 0u; }
    int r = blockIdx.x & 7;
    int k = blockIdx.x >> 3;
    int b = r + 8 * (k >> 10);
    int pix = (k & 1023) * 256 + threadIdx.x;
    long base = (long)b * 3 * 262144 + pix;

    float p0 = pred[base], p1 = pred[base + 262144], p2 = pred[base + 2 * 262144];
    bool fgP = ((p0 + 1.0f) * 0.5f >= 0.7f) ||
               ((p1 + 1.0f) * 0.5f >= 0.7f) ||
               ((p2 + 1.0f) * 0.5f >= 0.7f);

    float t0 = tgt[base], t1 = tgt[base + 262144], t2 = tgt[base + 2 * 262144];
    float mt = fmaxf(fmaxf(t0, t1), t2);

    bufA[(long)b * 262144 + pix]        = fgP ? 0.0f : VF;
    bufA[(long)(16 + b) * 262144 + pix] = VF * (1.0f - mt);
}

// ---------------------------------------------------------------------------
// K2: chamfer sweep, one wave per map, 3-bank group-pipelined prefetch.
// Bank B[g%3] is consumed during group g while bank B[(g+2)%3] is being
// loaded (16 dwordx4 issued as one burst, ~2 group-times ahead of use).
// Compile-time bank indices keep everything in VGPRs (~220).
// ---------------------------------------------------------------------------
__device__ __forceinline__ void load_row8(const float* __restrict__ M, int r, int c0, float v[8])
{
    const float4* q = (const float4*)(M + ((long)r << 9) + c0);
    float4 a = q[0], b = q[1];
    v[0] = a.x; v[1] = a.y; v[2] = a.z; v[3] = a.w;
    v[4] = b.x; v[5] = b.y; v[6] = b.z; v[7] = b.w;
}

__device__ __forceinline__ void store_row8(float* __restrict__ M, int r, int c0, const float v[8])
{
    float4* q = (float4*)(M + ((long)r << 9) + c0);
    q[0] = make_float4(v[0], v[1], v[2], v[3]);
    q[1] = make_float4(v[4], v[5], v[6], v[7]);
}

// One group: prefetch rows [rowbase+16 .. rowbase+23] into `pref`,
// then compute rows [rowbase .. rowbase+LIM-1] out of `cons`.
template<int DIR, bool TRACK, bool TAIL>
__device__ __forceinline__ void group_once(const float* __restrict__ S,
                                           float* __restrict__ D,
                                           int c0, int rowbase,
                                           float (&cons)[8][8], float (&pref)[8][8],
                                           float p[8], float& mn, float& mx)
{
    constexpr int start = (DIR > 0) ? 1 : 510;
    if (!TAIL) {
        #pragma unroll
        for (int k = 0; k < 8; ++k) {
            int off = rowbase + 16 + k;
            if (off > 510) off = 510;
            load_row8(S, start + off * DIR, c0, pref[k]);
        }
    }
    constexpr int LIM = TAIL ? 7 : 8;
    #pragma unroll
    for (int k = 0; k < LIM; ++k) {
        const int r = start + (rowbase + k) * DIR;
        float left  = dpp_left(p[7]);
        float right = dpp_right(p[0]);
        float nv[8];
        #pragma unroll
        for (int j = 0; j < 8; ++j) {
            float l  = (j == 0) ? left  : p[j - 1];
            float rr = (j == 7) ? right : p[j + 1];
            nv[j] = fminf(fminf(cons[k][j], p[j] + 1.0f), fminf(l, rr) + SQ2);
        }
        store_row8(D, r, c0, nv);
        #pragma unroll
        for (int j = 0; j < 8; ++j) {
            p[j] = nv[j];
            if (TRACK) { mn = fminf(mn, nv[j]); mx = fmaxf(mx, nv[j]); }
        }
    }
}

template<int DIR, bool TRACK>
__device__ __forceinline__ void sweep_dir(const float* __restrict__ S,
                                          float* __restrict__ D,
                                          int c0, float p[8], float& mn, float& mx)
{
    float bank[3][8][8];
    constexpr int start = (DIR > 0) ? 1 : 510;
    #pragma unroll
    for (int k = 0; k < 8; ++k) load_row8(S, start + k * DIR,       c0, bank[0][k]);
    #pragma unroll
    for (int k = 0; k < 8; ++k) load_row8(S, start + (8 + k) * DIR, c0, bank[1][k]);

    // 63 full groups (rows 0..503), bank pattern period 3 aligned to gg.
    #pragma unroll 1
    for (int gg = 0; gg < 21; ++gg) {
        int rb = 24 * gg;
        group_once<DIR, TRACK, false>(S, D, c0, rb,      bank[0], bank[2], p, mn, mx);
        group_once<DIR, TRACK, false>(S, D, c0, rb + 8,  bank[1], bank[0], p, mn, mx);
        group_once<DIR, TRACK, false>(S, D, c0, rb + 16, bank[2], bank[1], p, mn, mx);
    }
    // tail group 63: rows 504..510 live in bank[0] (prefetched at g=61)
    group_once<DIR, TRACK, true>(S, D, c0, 504, bank[0], bank[1], p, mn, mx);
}

__global__ __launch_bounds__(64, 1) void k_sweep(float* __restrict__ X0,
                                                 float* __restrict__ Y0,
                                                 float* __restrict__ minmax,
                                                 int final_pass)
{
    float* X = X0 + ((long)blockIdx.x << 18);
    float* Y = Y0 + ((long)blockIdx.x << 18);
    const int c0 = (int)threadIdx.x << 3;

    float p[8];
    float mn = BIGF, mx = -BIGF;

    // down: X -> Y  (row 0 copied unchanged, reference semantics)
    load_row8(X, 0, c0, p);
    store_row8(Y, 0, c0, p);
    sweep_dir<1, false>(X, Y, c0, p, mn, mx);   // p = new row 511 (== Y[511])
    __threadfence_block();

    // up: Y -> X  (row 511 copied unchanged; p already holds it)
    store_row8(X, 511, c0, p);
    if (final_pass) {
        #pragma unroll
        for (int j = 0; j < 8; ++j) { mn = fminf(mn, p[j]); mx = fmaxf(mx, p[j]); }
        sweep_dir<-1, true>(Y, X, c0, p, mn, mx);
        for (int o = 32; o > 0; o >>= 1) {
            mn = fminf(mn, __shfl_down(mn, o));
            mx = fmaxf(mx, __shfl_down(mx, o));
        }
        if (threadIdx.x == 0) { minmax[2 * blockIdx.x] = mn; minmax[2 * blockIdx.x + 1] = mx; }
    } else {
        sweep_dir<-1, false>(Y, X, c0, p, mn, mx);
    }
}

// ---------------------------------------------------------------------------
// K3: transpose, 64x64 tiles.
// ---------------------------------------------------------------------------
__global__ __launch_bounds__(256) void k_transpose(const float* __restrict__ src,
                                                   float* __restrict__ dst)
{
    __shared__ float tile[64][65];
    int r = blockIdx.x & 7;
    int k = blockIdx.x >> 3;
    int m = r + 8 * (k >> 6);
    int tidx = k & 63;
    int ti = tidx >> 3, tj = tidx & 7;
    const float* S = src + ((long)m << 18);
    float*       D = dst + ((long)m << 18);
    int x = threadIdx.x & 63, y0 = threadIdx.x >> 6;
    #pragma unroll
    for (int kk = 0; kk < 16; ++kk) {
        int y = y0 + (kk << 2);
        tile[y][x] = S[(ti * 64 + y) * 512 + tj * 64 + x];
    }
    __syncthreads();
    #pragma unroll
    for (int kk = 0; kk < 16; ++kk) {
        int y = y0 + (kk << 2);
        D[(tj * 64 + y) * 512 + ti * 64 + x] = tile[x][y];
    }
}

// ---------------------------------------------------------------------------
// K4: register-blocked bitonic sort (8 elems/thread) + MSE + fused finalize.
// ---------------------------------------------------------------------------
__device__ __forceinline__ void ce(float& a, float& b, bool up)
{
    float lo = fminf(a, b), hi = fmaxf(a, b);
    a = up ? lo : hi;
    b = up ? hi : lo;
}

__device__ __forceinline__ void merge8(float v[8], bool up)
{
    ce(v[0], v[4], up); ce(v[1], v[5], up); ce(v[2], v[6], up); ce(v[3], v[7], up);
    ce(v[0], v[2], up); ce(v[1], v[3], up); ce(v[4], v[6], up); ce(v[5], v[7], up);
    ce(v[0], v[1], up); ce(v[2], v[3], up); ce(v[4], v[5], up); ce(v[6], v[7], up);
}

__device__ __forceinline__ void sort8(float v[8], bool u8)
{
    ce(v[0], v[1], true);  ce(v[2], v[3], false);
    ce(v[4], v[5], true);  ce(v[6], v[7], false);
    ce(v[0], v[2], true);  ce(v[1], v[3], true);
    ce(v[4], v[6], false); ce(v[5], v[7], false);
    ce(v[0], v[1], true);  ce(v[2], v[3], true);
    ce(v[4], v[5], false); ce(v[6], v[7], false);
    merge8(v, u8);
}

__device__ __forceinline__ void xstage(float v[8], int j8, bool keepmin)
{
    #pragma unroll
    for (int e = 0; e < 8; ++e) {
        float o = __shfl_xor(v[e], j8);
        v[e] = keepmin ? fminf(v[e], o) : fmaxf(v[e], o);
    }
}

__device__ __forceinline__ void lstage2(float p[8], float q[8], int j8, bool keepmin,
                                        float* sp, float* st, int t)
{
    __syncthreads();
    float4* wp = (float4*)(sp + t * 8);
    float4* wq = (float4*)(st + t * 8);
    wp[0] = make_float4(p[0], p[1], p[2], p[3]);
    wp[1] = make_float4(p[4], p[5], p[6], p[7]);
    wq[0] = make_float4(q[0], q[1], q[2], q[3]);
    wq[1] = make_float4(q[4], q[5], q[6], q[7]);
    __syncthreads();
    int pt = t ^ j8;
    const float4* rp = (const float4*)(sp + pt * 8);
    const float4* rq = (const float4*)(st + pt * 8);
    float4 a = rp[0], bb = rp[1], c = rq[0], d = rq[1];
    float op[8] = {a.x, a.y, a.z, a.w, bb.x, bb.y, bb.z, bb.w};
    float oq[8] = {c.x, c.y, c.z, c.w, d.x, d.y, d.z, d.w};
    #pragma unroll
    for (int e = 0; e < 8; ++e) {
        p[e] = keepmin ? fminf(p[e], op[e]) : fmaxf(p[e], op[e]);
        q[e] = keepmin ? fminf(q[e], oq[e]) : fmaxf(q[e], oq[e]);
    }
}

__global__ __launch_bounds__(512) void k_loss(const float* __restrict__ bufB,
                                              const float* __restrict__ minmax,
                                              float* __restrict__ acc,
                                              unsigned* __restrict__ count,
                                              float* __restrict__ out)
{
    __shared__ float sp[4096];
    __shared__ float st[4096];
    __shared__ float rs[8];

    int t = threadIdx.x;
    int r = blockIdx.x & 7;
    int k = blockIdx.x >> 3;
    int b = r + 8 * (k >> 6);
    int w = k & 63;
    int wi = w >> 3, wj = w & 7;

    int i0 = t << 3;
    int y = wi * 64 + (i0 >> 6);
    int x = wj * 64 + (i0 & 63);

    float mnP = minmax[2 * b],        mxP = minmax[2 * b + 1];
    float mnT = minmax[2 * (16 + b)], mxT = minmax[2 * (16 + b) + 1];
    float sclP = 1.0f / (mxP - mnP + 1e-6f);
    float sclT = 1.0f / (mxT - mnT + 1e-6f);

    float p[8], q[8];
    {
        const float4* P4 = (const float4*)(bufB + (long)b * 262144 + y * 512 + x);
        const float4* T4 = (const float4*)(bufB + (long)(16 + b) * 262144 + y * 512 + x);
        float4 a = P4[0], bb = P4[1], c = T4[0], d = T4[1];
        p[0]=a.x; p[1]=a.y; p[2]=a.z; p[3]=a.w; p[4]=bb.x; p[5]=bb.y; p[6]=bb.z; p[7]=bb.w;
        q[0]=c.x; q[1]=c.y; q[2]=c.z; q[3]=c.w; q[4]=d.x;  q[5]=d.y;  q[6]=d.z;  q[7]=d.w;
        #pragma unroll
        for (int e = 0; e < 8; ++e) {
            p[e] = (p[e] - mnP) * sclP;
            q[e] = (q[e] - mnT) * sclT;
        }
    }

    bool u8 = ((t & 1) == 0);
    sort8(p, u8);
    sort8(q, u8);

    for (int kk = 16; kk <= 4096; kk <<= 1) {
        bool u = ((i0 & kk) == 0);
        for (int j = kk >> 1; j >= 8; j >>= 1) {
            bool l = ((i0 & j) == 0);
            bool keepmin = (u == l);
            int j8 = j >> 3;
            if (j8 < 64) {
                xstage(p, j8, keepmin);
                xstage(q, j8, keepmin);
            } else {
                lstage2(p, q, j8, keepmin, sp, st, t);
            }
        }
        merge8(p, u);
        merge8(q, u);
    }

    float s = 0.0f;
    #pragma unroll
    for (int e = 0; e < 8; ++e) { float d = p[e] - q[e]; s += d * d; }
    for (int o = 32; o > 0; o >>= 1) s += __shfl_down(s, o);
    if ((t & 63) == 0) rs[t >> 6] = s;
    __syncthreads();
    if (t == 0) {
        float tot = 0.0f;
        #pragma unroll
        for (int i = 0; i < 8; ++i) tot += rs[i];
        atomicAdd(acc, tot);
        __threadfence();
        unsigned done = atomicAdd(count, 1u);
        if (done == 1023u) {
            float total = atomicAdd(acc, 0.0f);
            float mean = total * (1.0f / 4194304.0f);
            out[0] = mean * 0.005f;
            out[1] = mean;
        }
    }
}

extern "C" void kernel_launch(void* const* d_in, const int* in_sizes, int n_in,
                              void* d_out, int out_size, void* d_ws, size_t ws_size,
                              hipStream_t stream)
{
    const float* pred = (const float*)d_in[0];
    const float* tgt  = (const float*)d_in[1];
    float* out = (float*)d_out;

    char* ws = (char*)d_ws;
    float* bufA     = (float*)ws;                     // 32 MB
    float* bufB     = (float*)(ws + (32ull << 20));   // 32 MB
    float* minmax   = (float*)(ws + (64ull << 20));   // 64 floats
    float* acc      = minmax + 64;
    unsigned* count = (unsigned*)(acc + 1);

    k_init     <<<16 * 1024, 256, 0, stream>>>(pred, tgt, bufA, acc, count);
    k_sweep    <<<32,  64,  0, stream>>>(bufA, bufB, minmax, 0);  // rows it1 -> A
    k_transpose<<<2048, 256, 0, stream>>>(bufA, bufB);            // A -> B
    k_sweep    <<<32,  64,  0, stream>>>(bufB, bufA, minmax, 0);  // cols it1 -> B
    k_transpose<<<2048, 256, 0, stream>>>(bufB, bufA);            // B -> A
    k_sweep    <<<32,  64,  0, stream>>>(bufA, bufB, minmax, 0);  // rows it2 -> A
    k_transpose<<<2048, 256, 0, stream>>>(bufA, bufB);            // A -> B
    k_sweep    <<<32,  64,  0, stream>>>(bufB, bufA, minmax, 1);  // cols it2 -> B (+minmax)
    k_loss     <<<1024, 512, 0, stream>>>(bufB, minmax, acc, count, out);
}